// Round 6
// baseline (140.892 us; speedup 1.0000x reference)
//
#include <hip/hip_runtime.h>
#include <hip/hip_bf16.h>

#define E_TOT 50000
#define NF    64
#define B_TOT 64
#define B_TILE 4
#define E_PT   4
#define BLOCK  128
#define EPB   (BLOCK * E_PT)   // 512 e per block

// out[b,e] = sum_f exp(-(HL[b,f] - NL[e,f] - c[f])^2 / var[f]) * W[b,f]
// q[f]=sqrt(log2e/var[f]); A[b,f]=(HL-c)*q; n=NL*q; phi=exp2(-(A-n)^2)
// R6: E_PT=4 e's per thread so each broadcast ds_read_b128 of A/W serves
// 4x the elements (LDS pipe 1.8M->0.45M reads, off critical path).
// Target bottleneck: combined VALU+trans issue (~14 cyc/elem wave64).
// 16 acc chains/thread hide exp latency at low wave count.
__global__ __launch_bounds__(BLOCK, 6)
void kbln_kernel(const float* __restrict__ NL,       // [E, F]
                 const float* __restrict__ c,        // [F]
                 const float* __restrict__ varr,     // [F]
                 const float* __restrict__ NFW,      // [R, F]
                 const int*   __restrict__ head_ids, // [B]
                 const int*   __restrict__ rel_ids,  // [B]
                 float*       __restrict__ out)      // [B, E]
{
    __shared__ float sQ[NF];
    __shared__ float4 sA[B_TILE][NF / 4];
    __shared__ float4 sW[B_TILE][NF / 4];

    const int tid = threadIdx.x;
    const int b0  = blockIdx.y * B_TILE;

    if (tid < NF) {
        sQ[tid] = sqrtf(1.4426950408889634f / varr[tid]);
    }
    __syncthreads();

    // Stage folded head literals A and weights W for this block's 4 b's.
    for (int s = tid; s < B_TILE * NF; s += BLOCK) {
        const int bi = s >> 6;
        const int f  = s & (NF - 1);
        const int h  = head_ids[b0 + bi];
        const int r  = rel_ids[b0 + bi];
        reinterpret_cast<float*>(&sA[bi][0])[f] =
            (NL[(size_t)h * NF + f] - c[f]) * sQ[f];
        reinterpret_cast<float*>(&sW[bi][0])[f] = NFW[(size_t)r * NF + f];
    }
    __syncthreads();

    // This thread's 4 e's (stride BLOCK keeps each load instr coalesced).
    int  e[E_PT];
    bool ok[E_PT];
    const float4* nl4[E_PT];
#pragma unroll
    for (int j = 0; j < E_PT; ++j) {
        e[j]  = blockIdx.x * EPB + j * BLOCK + tid;
        ok[j] = (e[j] < E_TOT);
        const int ec = ok[j] ? e[j] : (E_TOT - 1);   // clamp OOB loads
        nl4[j] = reinterpret_cast<const float4*>(NL + (size_t)ec * NF);
    }

    const float4* q4 = reinterpret_cast<const float4*>(sQ);

    float acc[E_PT][B_TILE];
#pragma unroll
    for (int j = 0; j < E_PT; ++j)
#pragma unroll
        for (int bi = 0; bi < B_TILE; ++bi) acc[j][bi] = 0.0f;

#pragma unroll 4
    for (int i = 0; i < NF / 4; ++i) {
        const float4 q = q4[i];
        float4 n[E_PT];
#pragma unroll
        for (int j = 0; j < E_PT; ++j) {
            const float4 v = nl4[j][i];
            n[j].x = v.x * q.x; n[j].y = v.y * q.y;
            n[j].z = v.z * q.z; n[j].w = v.w * q.w;
        }
#pragma unroll
        for (int bi = 0; bi < B_TILE; ++bi) {
            const float4 a = sA[bi][i];   // broadcast ds_read_b128
            const float4 w = sW[bi][i];
#pragma unroll
            for (int j = 0; j < E_PT; ++j) {
                float t;
                t = a.x - n[j].x; acc[j][bi] = fmaf(__builtin_amdgcn_exp2f(-(t * t)), w.x, acc[j][bi]);
                t = a.y - n[j].y; acc[j][bi] = fmaf(__builtin_amdgcn_exp2f(-(t * t)), w.y, acc[j][bi]);
                t = a.z - n[j].z; acc[j][bi] = fmaf(__builtin_amdgcn_exp2f(-(t * t)), w.z, acc[j][bi]);
                t = a.w - n[j].w; acc[j][bi] = fmaf(__builtin_amdgcn_exp2f(-(t * t)), w.w, acc[j][bi]);
            }
        }
    }

#pragma unroll
    for (int bi = 0; bi < B_TILE; ++bi)
#pragma unroll
        for (int j = 0; j < E_PT; ++j)
            if (ok[j]) out[(size_t)(b0 + bi) * E_TOT + e[j]] = acc[j][bi];
}

extern "C" void kernel_launch(void* const* d_in, const int* in_sizes, int n_in,
                              void* d_out, int out_size, void* d_ws, size_t ws_size,
                              hipStream_t stream)
{
    const float* NL       = (const float*)d_in[0];
    const float* c        = (const float*)d_in[1];
    const float* varr     = (const float*)d_in[2];
    const float* NFW      = (const float*)d_in[3];
    const int*   head_ids = (const int*)d_in[4];
    const int*   rel_ids  = (const int*)d_in[5];
    float*       out      = (float*)d_out;

    dim3 grid((E_TOT + EPB - 1) / EPB, B_TOT / B_TILE);
    kbln_kernel<<<grid, dim3(BLOCK), 0, stream>>>(NL, c, varr, NFW, head_ids, rel_ids, out);
}